// Round 1
// baseline (504.121 us; speedup 1.0000x reference)
//
#include <hip/hip_runtime.h>

typedef unsigned short ushort_t;
typedef __attribute__((ext_vector_type(8))) short short8;
typedef __attribute__((ext_vector_type(4))) float floatx4;

#define LOG2E 1.4426950408889634f

__device__ __forceinline__ unsigned short f2bf(float f) {
    unsigned u = __float_as_uint(f);
    u += 0x7FFF + ((u >> 16) & 1);   // RNE
    return (unsigned short)(u >> 16);
}

// CK-style double cast (generic -> int -> AS pointer); low 32 bits of a
// generic LDS pointer are the LDS offset on gfx9+.
__device__ __forceinline__ void async_ld16(const void* gptr, void* lptr) {
    typedef const __attribute__((address_space(1))) unsigned int TG;
    typedef __attribute__((address_space(3))) unsigned int TL;
    __builtin_amdgcn_global_load_lds((TG*)(unsigned long long)gptr,
                                     (TL*)(unsigned)(unsigned long long)lptr,
                                     16, 0, 0);
}

// ---------------- fp32 -> bf16 convert (vec4) ----------------
__global__ __launch_bounds__(256) void cvt_bf16_kernel(const float* __restrict__ in,
                                                       ushort_t* __restrict__ out, int n4) {
    int i = blockIdx.x * 256 + threadIdx.x;
    if (i >= n4) return;
    float4 v = ((const float4*)in)[i];
    unsigned long long r = (unsigned long long)f2bf(v.x)
                         | ((unsigned long long)f2bf(v.y) << 16)
                         | ((unsigned long long)f2bf(v.z) << 32)
                         | ((unsigned long long)f2bf(v.w) << 48);
    ((unsigned long long*)out)[i] = r;
}

// ---------------- fp32 [R][C] -> bf16 [C][R] (weights to B^T) ----------------
__global__ __launch_bounds__(256) void transpose_cvt_kernel(const float* __restrict__ in,
                                                            ushort_t* __restrict__ out,
                                                            int R, int C) {
    __shared__ float t[32][33];
    int nbc = C >> 5;
    int bc = blockIdx.x % nbc, br = blockIdx.x / nbc;
    int tx = threadIdx.x & 31, ty = threadIdx.x >> 5;   // 32 x 8
    int r0 = br << 5, c0 = bc << 5;
#pragma unroll
    for (int j = 0; j < 4; ++j)
        t[ty + j * 8][tx] = in[(size_t)(r0 + ty + j * 8) * C + c0 + tx];
    __syncthreads();
#pragma unroll
    for (int j = 0; j < 4; ++j)
        out[(size_t)(c0 + ty + j * 8) * R + r0 + tx] = f2bf(t[tx][ty + j * 8]);
}

// ---------------- V (bf16, inside qkv) -> Vt[bh][d][s] (kpos-contiguous) ----------------
__global__ __launch_bounds__(256) void transpose_v_kernel(const ushort_t* __restrict__ qkv,
                                                          ushort_t* __restrict__ vt) {
    int t = blockIdx.x * 256 + threadIdx.x;   // 1,048,576 threads
    int sb = t & 255;
    int d  = (t >> 8) & 63;
    int bh = t >> 14;
    int b = bh >> 4, h = bh & 15;
    int s0 = sb << 3;
    const ushort_t* src = qkv + (size_t)(b * 2048 + s0) * 3072 + 2048 + h * 64 + d;
    short8 v;
#pragma unroll
    for (int j = 0; j < 8; ++j) v[j] = (short)src[(size_t)j * 3072];
    *(short8*)(vt + (size_t)bh * (64 * 2048) + (size_t)d * 2048 + s0) = v;
}

// ---------------- m97-style bf16 GEMM, B^T input, 128x128 tile, BK=32 ----------------
// OUTF=0: bf16 out (+bias), OUTF=1: fp32 out (+bias)
template <int OUTF>
__global__ __launch_bounds__(256) void gemm_bt_kernel(const ushort_t* __restrict__ A,
                                                      const ushort_t* __restrict__ Bt,
                                                      const float* __restrict__ bias,
                                                      void* __restrict__ Cout,
                                                      int M, int N, int K, int nbn) {
    __shared__ __align__(16) ushort_t As[128 * 32];
    __shared__ __align__(16) ushort_t Bs[128 * 32];
    int bm = blockIdx.x / nbn, bn = blockIdx.x % nbn;
    int m0 = bm << 7, n0 = bn << 7;
    int tid = threadIdx.x;
    int wave = tid >> 6, lane = tid & 63;
    int c = lane & 15, g = lane >> 4;
    int m_off = (wave & 1) << 6, n_off = (wave >> 1) << 6;
    int ldrow = lane >> 2;          // 0..15
    int ldk   = (lane & 3) << 3;    // 0,8,16,24

    floatx4 acc[4][4];
#pragma unroll
    for (int mi = 0; mi < 4; ++mi)
#pragma unroll
        for (int ni = 0; ni < 4; ++ni) {
            floatx4 z = {0.f, 0.f, 0.f, 0.f};
            acc[mi][ni] = z;
        }

    for (int kk = 0; kk < K; kk += 32) {
        __syncthreads();
#pragma unroll
        for (int j = 0; j < 2; ++j) {
            int chunk = wave * 2 + j;                       // 0..7 (16 rows each)
            const ushort_t* ga = A  + (size_t)(m0 + chunk * 16 + ldrow) * K + kk + ldk;
            async_ld16(ga, &As[chunk * 512]);
            const ushort_t* gb = Bt + (size_t)(n0 + chunk * 16 + ldrow) * K + kk + ldk;
            async_ld16(gb, &Bs[chunk * 512]);
        }
        __syncthreads();

        short8 bf[4];
#pragma unroll
        for (int ni = 0; ni < 4; ++ni)
            bf[ni] = *(const short8*)&Bs[(n_off + ni * 16 + c) * 32 + g * 8];
#pragma unroll
        for (int mi = 0; mi < 4; ++mi) {
            short8 af = *(const short8*)&As[(m_off + mi * 16 + c) * 32 + g * 8];
#pragma unroll
            for (int ni = 0; ni < 4; ++ni)
                acc[mi][ni] = __builtin_amdgcn_mfma_f32_16x16x32_bf16(af, bf[ni], acc[mi][ni], 0, 0, 0);
        }
    }

    float bv[4];
#pragma unroll
    for (int ni = 0; ni < 4; ++ni) bv[ni] = bias[n0 + n_off + ni * 16 + c];
#pragma unroll
    for (int mi = 0; mi < 4; ++mi)
#pragma unroll
        for (int ni = 0; ni < 4; ++ni)
#pragma unroll
            for (int r = 0; r < 4; ++r) {
                int row = m0 + m_off + mi * 16 + g * 4 + r;
                int col = n0 + n_off + ni * 16 + c;
                float v = acc[mi][ni][r] + bv[ni];
                if (OUTF) ((float*)Cout)[(size_t)row * N + col] = v;
                else      ((ushort_t*)Cout)[(size_t)row * N + col] = f2bf(v);
            }
}

// ---------------- flash attention: 1 block = (b,h) x 64 q-rows ----------------
__global__ __launch_bounds__(256) void attn_kernel(const ushort_t* __restrict__ qkv,
                                                   const ushort_t* __restrict__ vt,
                                                   ushort_t* __restrict__ aout) {
    __shared__ __align__(16) ushort_t Ks[128 * 72];      // [kp][d], stride 72 (2-way max)
    __shared__ __align__(16) ushort_t Vs[64 * 136];      // [d][kp], stride 136
    __shared__ __align__(16) ushort_t Ps[4][16 * 136];   // per-wave P, stride 136
    int bx = blockIdx.x;
    int qb = bx & 31, h = (bx >> 5) & 15, b = bx >> 9;
    int q0 = qb << 6;
    int tid = threadIdx.x, wave = tid >> 6, lane = tid & 63;
    int c = lane & 15, g = lane >> 4;

    // Q fragments (A-operand: m = lane&15, k = (lane>>4)*8 + j), held in regs
    const ushort_t* qbase = qkv + (size_t)(b * 2048 + q0 + wave * 16 + c) * 3072 + h * 64;
    short8 qf0 = *(const short8*)(qbase + g * 8);
    short8 qf1 = *(const short8*)(qbase + 32 + g * 8);

    float m_i[4], l_i[4];
    floatx4 o_acc[4];
#pragma unroll
    for (int r = 0; r < 4; ++r) { m_i[r] = -1e30f; l_i[r] = 0.f; }
#pragma unroll
    for (int nt = 0; nt < 4; ++nt) { floatx4 z = {0.f,0.f,0.f,0.f}; o_acc[nt] = z; }

    int kt_end = (q0 + 63) >> 7;
    for (int kt = 0; kt <= kt_end; ++kt) {
        int kt0 = kt << 7;
        __syncthreads();
        // stage K tile [128][64] -> padded LDS
#pragma unroll
        for (int it = 0; it < 4; ++it) {
            int idx = it * 256 + tid;
            int kp = idx >> 3, d0 = (idx & 7) << 3;
            short8 kv = *(const short8*)(qkv + (size_t)(b * 2048 + kt0 + kp) * 3072 + 1024 + h * 64 + d0);
            *(short8*)&Ks[kp * 72 + d0] = kv;
        }
        // stage V^T tile [64][128] -> padded LDS (from pre-transposed vt)
#pragma unroll
        for (int it = 0; it < 4; ++it) {
            int idx = it * 256 + tid;
            int d = idx >> 4, s8 = (idx & 15) << 3;
            short8 vv = *(const short8*)(vt + (size_t)(b * 16 + h) * 131072 + d * 2048 + kt0 + s8);
            *(short8*)&Vs[d * 136 + s8] = vv;
        }
        __syncthreads();

        // S = Q @ K^T  (wave strip: 16 q x 128 kpos)
        floatx4 sacc[8];
#pragma unroll
        for (int nt = 0; nt < 8; ++nt) {
            floatx4 z = {0.f,0.f,0.f,0.f};
            short8 kf0 = *(const short8*)&Ks[(nt * 16 + c) * 72 + g * 8];
            z = __builtin_amdgcn_mfma_f32_16x16x32_bf16(qf0, kf0, z, 0, 0, 0);
            short8 kf1 = *(const short8*)&Ks[(nt * 16 + c) * 72 + 32 + g * 8];
            sacc[nt] = __builtin_amdgcn_mfma_f32_16x16x32_bf16(qf1, kf1, z, 0, 0, 0);
        }

        // scale + causal mask + row max (C layout: row = g*4+r, col = nt*16+c)
        float rmax[4] = {-1e30f, -1e30f, -1e30f, -1e30f};
        int qrow[4];
#pragma unroll
        for (int r = 0; r < 4; ++r) qrow[r] = q0 + wave * 16 + g * 4 + r;
#pragma unroll
        for (int nt = 0; nt < 8; ++nt) {
            int col = kt0 + nt * 16 + c;
#pragma unroll
            for (int r = 0; r < 4; ++r) {
                float s = sacc[nt][r] * 0.125f;
                s = (col > qrow[r]) ? -1e30f : s;
                sacc[nt][r] = s;
                rmax[r] = fmaxf(rmax[r], s);
            }
        }
#pragma unroll
        for (int r = 0; r < 4; ++r)
#pragma unroll
            for (int mk = 1; mk <= 8; mk <<= 1)
                rmax[r] = fmaxf(rmax[r], __shfl_xor(rmax[r], mk));

        float alpha[4], rsum[4], mnew[4];
#pragma unroll
        for (int r = 0; r < 4; ++r) {
            mnew[r] = fmaxf(m_i[r], rmax[r]);
            alpha[r] = exp2f((m_i[r] - mnew[r]) * LOG2E);
            m_i[r] = mnew[r];
            rsum[r] = 0.f;
        }
#pragma unroll
        for (int nt = 0; nt < 8; ++nt)
#pragma unroll
            for (int r = 0; r < 4; ++r) {
                float p = exp2f((sacc[nt][r] - mnew[r]) * LOG2E);
                rsum[r] += p;
                Ps[wave][(g * 4 + r) * 136 + nt * 16 + c] = f2bf(p);
            }
#pragma unroll
        for (int r = 0; r < 4; ++r) {
#pragma unroll
            for (int mk = 1; mk <= 8; mk <<= 1)
                rsum[r] += __shfl_xor(rsum[r], mk);
            l_i[r] = l_i[r] * alpha[r] + rsum[r];
        }
#pragma unroll
        for (int nt = 0; nt < 4; ++nt)
#pragma unroll
            for (int r = 0; r < 4; ++r)
                o_acc[nt][r] *= alpha[r];

        // O += P @ V   (A = P from LDS, B^T = Vs)
#pragma unroll
        for (int ks = 0; ks < 4; ++ks) {
            short8 pf = *(const short8*)&Ps[wave][c * 136 + ks * 32 + g * 8];
#pragma unroll
            for (int nt = 0; nt < 4; ++nt) {
                short8 vf = *(const short8*)&Vs[(nt * 16 + c) * 136 + ks * 32 + g * 8];
                o_acc[nt] = __builtin_amdgcn_mfma_f32_16x16x32_bf16(pf, vf, o_acc[nt], 0, 0, 0);
            }
        }
    }

    // epilogue: O / l -> a[b][s][h*64+d] (bf16)
#pragma unroll
    for (int nt = 0; nt < 4; ++nt)
#pragma unroll
        for (int r = 0; r < 4; ++r) {
            int q = q0 + wave * 16 + g * 4 + r;
            float v = o_acc[nt][r] / l_i[r];
            aout[(size_t)(b * 2048 + q) * 1024 + h * 64 + nt * 16 + c] = f2bf(v);
        }
}

extern "C" void kernel_launch(void* const* d_in, const int* in_sizes, int n_in,
                              void* d_out, int out_size, void* d_ws, size_t ws_size,
                              hipStream_t stream) {
    const float* x        = (const float*)d_in[0];
    const float* c_attn_w = (const float*)d_in[1];
    const float* c_attn_b = (const float*)d_in[2];
    const float* c_proj_w = (const float*)d_in[3];
    const float* c_proj_b = (const float*)d_in[4];
    float* out = (float*)d_out;

    char* ws = (char*)d_ws;
    ushort_t* xb     = (ushort_t*)(ws);              // 8192x1024 bf16; later reused as attn-out 'a'
    ushort_t* wqkvT  = (ushort_t*)(ws + 16777216);   // 3072x1024 bf16 (B^T)
    ushort_t* wprojT = (ushort_t*)(ws + 23068672);   // 1024x1024 bf16 (B^T)
    ushort_t* qkv    = (ushort_t*)(ws + 25165824);   // 8192x3072 bf16
    ushort_t* vtw    = (ushort_t*)(ws + 75497472);   // 64 x 64 x 2048 bf16 (V^T per head)

    cvt_bf16_kernel<<<8192, 256, 0, stream>>>(x, xb, 2097152);
    transpose_cvt_kernel<<<32 * 96, 256, 0, stream>>>(c_attn_w, wqkvT, 1024, 3072);
    transpose_cvt_kernel<<<32 * 32, 256, 0, stream>>>(c_proj_w, wprojT, 1024, 1024);
    gemm_bt_kernel<0><<<64 * 24, 256, 0, stream>>>(xb, wqkvT, c_attn_b, qkv, 8192, 3072, 1024, 24);
    transpose_v_kernel<<<4096, 256, 0, stream>>>(qkv, vtw);
    attn_kernel<<<2048, 256, 0, stream>>>(qkv, vtw, xb);   // writes 'a' over xb (xb dead after gemm1)
    gemm_bt_kernel<1><<<64 * 8, 256, 0, stream>>>(xb, wprojT, c_proj_b, out, 8192, 1024, 1024, 8);
}

// Round 2
// 405.988 us; speedup vs baseline: 1.2417x; 1.2417x over previous
//
#include <hip/hip_runtime.h>

typedef unsigned short ushort_t;
typedef __attribute__((ext_vector_type(8))) short short8;
typedef __attribute__((ext_vector_type(4))) float floatx4;

#define LOG2E 1.4426950408889634f

__device__ __forceinline__ unsigned short f2bf(float f) {
    unsigned u = __float_as_uint(f);
    u += 0x7FFF + ((u >> 16) & 1);   // RNE
    return (unsigned short)(u >> 16);
}

__device__ __forceinline__ void async_ld16(const void* gptr, void* lptr) {
    typedef const __attribute__((address_space(1))) unsigned int TG;
    typedef __attribute__((address_space(3))) unsigned int TL;
    __builtin_amdgcn_global_load_lds((TG*)(unsigned long long)gptr,
                                     (TL*)(unsigned)(unsigned long long)lptr,
                                     16, 0, 0);
}

// ---------------- fp32 -> bf16 convert (vec4) ----------------
__global__ __launch_bounds__(256) void cvt_bf16_kernel(const float* __restrict__ in,
                                                       ushort_t* __restrict__ out, int n4) {
    int i = blockIdx.x * 256 + threadIdx.x;
    if (i >= n4) return;
    float4 v = ((const float4*)in)[i];
    unsigned long long r = (unsigned long long)f2bf(v.x)
                         | ((unsigned long long)f2bf(v.y) << 16)
                         | ((unsigned long long)f2bf(v.z) << 32)
                         | ((unsigned long long)f2bf(v.w) << 48);
    ((unsigned long long*)out)[i] = r;
}

// ---------------- fp32 [R][C] -> bf16 [C][R] (weights to B^T) ----------------
__global__ __launch_bounds__(256) void transpose_cvt_kernel(const float* __restrict__ in,
                                                            ushort_t* __restrict__ out,
                                                            int R, int C) {
    __shared__ float t[32][33];
    int nbc = C >> 5;
    int bc = blockIdx.x % nbc, br = blockIdx.x / nbc;
    int tx = threadIdx.x & 31, ty = threadIdx.x >> 5;   // 32 x 8
    int r0 = br << 5, c0 = bc << 5;
#pragma unroll
    for (int j = 0; j < 4; ++j)
        t[ty + j * 8][tx] = in[(size_t)(r0 + ty + j * 8) * C + c0 + tx];
    __syncthreads();
#pragma unroll
    for (int j = 0; j < 4; ++j)
        out[(size_t)(c0 + ty + j * 8) * R + r0 + tx] = f2bf(t[tx][ty + j * 8]);
}

// ---------------- QKV GEMM: [8192,1024]@[1024,3072]^T + bias -> split Q/K/Vt ----------------
// Q,K: [bh][s][64] bf16 ; Vt: [bh][64][2048] bf16
__global__ __launch_bounds__(256) void gemm_qkv_kernel(const ushort_t* __restrict__ A,
                                                       const ushort_t* __restrict__ Bt,
                                                       const float* __restrict__ bias,
                                                       ushort_t* __restrict__ qbuf,
                                                       ushort_t* __restrict__ kbuf,
                                                       ushort_t* __restrict__ vtbuf) {
    const int K = 1024, nbn = 24;
    __shared__ __align__(16) ushort_t As[128 * 32];
    __shared__ __align__(16) ushort_t Bs[128 * 32];
    int bm = blockIdx.x / nbn, bn = blockIdx.x % nbn;
    int m0 = bm << 7, n0 = bn << 7;
    int tid = threadIdx.x;
    int wave = tid >> 6, lane = tid & 63;
    int c = lane & 15, g = lane >> 4;
    int m_off = (wave & 1) << 6, n_off = (wave >> 1) << 6;
    int ldrow = lane >> 2;
    int ldk   = (lane & 3) << 3;

    floatx4 acc[4][4];
#pragma unroll
    for (int mi = 0; mi < 4; ++mi)
#pragma unroll
        for (int ni = 0; ni < 4; ++ni) {
            floatx4 z = {0.f, 0.f, 0.f, 0.f};
            acc[mi][ni] = z;
        }

    for (int kk = 0; kk < K; kk += 32) {
        __syncthreads();
#pragma unroll
        for (int j = 0; j < 2; ++j) {
            int chunk = wave * 2 + j;
            async_ld16(A  + (size_t)(m0 + chunk * 16 + ldrow) * K + kk + ldk, &As[chunk * 512]);
            async_ld16(Bt + (size_t)(n0 + chunk * 16 + ldrow) * K + kk + ldk, &Bs[chunk * 512]);
        }
        __syncthreads();
        short8 bf[4];
#pragma unroll
        for (int ni = 0; ni < 4; ++ni)
            bf[ni] = *(const short8*)&Bs[(n_off + ni * 16 + c) * 32 + g * 8];
#pragma unroll
        for (int mi = 0; mi < 4; ++mi) {
            short8 af = *(const short8*)&As[(m_off + mi * 16 + c) * 32 + g * 8];
#pragma unroll
            for (int ni = 0; ni < 4; ++ni)
                acc[mi][ni] = __builtin_amdgcn_mfma_f32_16x16x32_bf16(af, bf[ni], acc[mi][ni], 0, 0, 0);
        }
    }

    int sec = n0 >> 10;               // 0=Q 1=K 2=V (block-uniform; 1024%128==0)
    float bv[4]; int hh[4], dd[4];
#pragma unroll
    for (int ni = 0; ni < 4; ++ni) {
        int coln = n0 + n_off + ni * 16 + c;
        bv[ni] = bias[coln];
        int coll = coln & 1023;
        hh[ni] = coll >> 6; dd[ni] = coll & 63;
    }
#pragma unroll
    for (int mi = 0; mi < 4; ++mi) {
        int rowb = m0 + m_off + mi * 16 + g * 4;     // +r
        int bb = rowb >> 11, sbase = rowb & 2047;
#pragma unroll
        for (int ni = 0; ni < 4; ++ni) {
            size_t bhn = (size_t)(bb * 16 + hh[ni]);
            if (sec == 2) {
                unsigned long long pk = 0;
#pragma unroll
                for (int r = 0; r < 4; ++r)
                    pk |= (unsigned long long)f2bf(acc[mi][ni][r] + bv[ni]) << (16 * r);
                *(unsigned long long*)(vtbuf + bhn * 131072 + (size_t)dd[ni] * 2048 + sbase) = pk;
            } else {
                ushort_t* dst = (sec == 0 ? qbuf : kbuf) + (bhn * 2048 + sbase) * 64 + dd[ni];
#pragma unroll
                for (int r = 0; r < 4; ++r)
                    dst[r * 64] = f2bf(acc[mi][ni][r] + bv[ni]);
            }
        }
    }
}

// ---------------- flash attention: 1 block = (b,h) x 128 q-rows, reg-prefetch pipeline ----------------
__global__ __launch_bounds__(256) void attn_kernel(const ushort_t* __restrict__ qb_,
                                                   const ushort_t* __restrict__ kb_,
                                                   const ushort_t* __restrict__ vtb_,
                                                   ushort_t* __restrict__ aout) {
    __shared__ __align__(16) ushort_t Ks[128 * 72];      // [kp][d] pad 72
    __shared__ __align__(16) ushort_t Vs[64 * 136];      // [d][kp] pad 136
    __shared__ __align__(16) ushort_t Ps[4][16 * 136];   // per-wave P strip
    int bx = blockIdx.x;
    int qb = bx & 15, h = (bx >> 4) & 15, b = bx >> 8;
    int q0 = qb << 7;
    int tid = threadIdx.x, wave = tid >> 6, lane = tid & 63;
    int c = lane & 15, g = lane >> 4;
    size_t bh = (size_t)(b * 16 + h);

    const ushort_t* Qp = qb_ + (bh * 2048 + q0) * 64;
    const ushort_t* Kp = kb_ + bh * 131072;
    const ushort_t* Vp = vtb_ + bh * 131072;

    short8 qf[2][2];
#pragma unroll
    for (int ss = 0; ss < 2; ++ss) {
        int qr = (wave * 2 + ss) * 16 + c;
        qf[ss][0] = *(const short8*)(Qp + qr * 64 + g * 8);
        qf[ss][1] = *(const short8*)(Qp + qr * 64 + 32 + g * 8);
    }

    float m_i[2][4], l_i[2][4];
    floatx4 o_acc[2][4];
#pragma unroll
    for (int ss = 0; ss < 2; ++ss)
#pragma unroll
        for (int r = 0; r < 4; ++r) { m_i[ss][r] = -1e30f; l_i[ss][r] = 0.f; }
#pragma unroll
    for (int ss = 0; ss < 2; ++ss)
#pragma unroll
        for (int nt = 0; nt < 4; ++nt) { floatx4 z = {0.f,0.f,0.f,0.f}; o_acc[ss][nt] = z; }

    // prefetch tile 0 into regs
    short8 kreg[4], vreg[4];
#pragma unroll
    for (int it = 0; it < 4; ++it) {
        int idx = it * 256 + tid;
        kreg[it] = *(const short8*)(Kp + idx * 8);
        vreg[it] = *(const short8*)(Vp + (idx >> 4) * 2048 + (idx & 15) * 8);
    }

    const float SC = 0.125f * LOG2E;
    for (int kt = 0; kt <= qb; ++kt) {
        __syncthreads();
#pragma unroll
        for (int it = 0; it < 4; ++it) {
            int idx = it * 256 + tid;
            *(short8*)&Ks[(idx >> 3) * 72 + (idx & 7) * 8] = kreg[it];
            *(short8*)&Vs[(idx >> 4) * 136 + (idx & 15) * 8] = vreg[it];
        }
        if (kt < qb) {  // prefetch next tile (overlaps this tile's compute)
            int s0 = (kt + 1) << 7;
#pragma unroll
            for (int it = 0; it < 4; ++it) {
                int idx = it * 256 + tid;
                kreg[it] = *(const short8*)(Kp + s0 * 64 + idx * 8);
                vreg[it] = *(const short8*)(Vp + (idx >> 4) * 2048 + s0 + (idx & 15) * 8);
            }
        }
        __syncthreads();
        bool diag = (kt == qb);

#pragma unroll
        for (int ss = 0; ss < 2; ++ss) {
            int rl0 = (wave * 2 + ss) * 16;
            floatx4 sacc[8];
#pragma unroll
            for (int nt = 0; nt < 8; ++nt) {
                floatx4 z = {0.f, 0.f, 0.f, 0.f};
                short8 kf0 = *(const short8*)&Ks[(nt * 16 + c) * 72 + g * 8];
                z = __builtin_amdgcn_mfma_f32_16x16x32_bf16(qf[ss][0], kf0, z, 0, 0, 0);
                short8 kf1 = *(const short8*)&Ks[(nt * 16 + c) * 72 + 32 + g * 8];
                sacc[nt] = __builtin_amdgcn_mfma_f32_16x16x32_bf16(qf[ss][1], kf1, z, 0, 0, 0);
            }

            float rmax[4] = {-1e30f, -1e30f, -1e30f, -1e30f};
            if (diag) {
#pragma unroll
                for (int nt = 0; nt < 8; ++nt) {
                    int cl = nt * 16 + c;
#pragma unroll
                    for (int r = 0; r < 4; ++r) {
                        float s = sacc[nt][r] * SC;
                        s = (cl > rl0 + g * 4 + r) ? -1e30f : s;
                        sacc[nt][r] = s;
                        rmax[r] = fmaxf(rmax[r], s);
                    }
                }
            } else {
#pragma unroll
                for (int nt = 0; nt < 8; ++nt)
#pragma unroll
                    for (int r = 0; r < 4; ++r) {
                        float s = sacc[nt][r] * SC;
                        sacc[nt][r] = s;
                        rmax[r] = fmaxf(rmax[r], s);
                    }
            }
#pragma unroll
            for (int r = 0; r < 4; ++r)
#pragma unroll
                for (int mk = 1; mk <= 8; mk <<= 1)
                    rmax[r] = fmaxf(rmax[r], __shfl_xor(rmax[r], mk));

            float mnew[4], alpha[4], rsum[4];
#pragma unroll
            for (int r = 0; r < 4; ++r) {
                mnew[r] = fmaxf(m_i[ss][r], rmax[r]);
                alpha[r] = exp2f(m_i[ss][r] - mnew[r]);
                m_i[ss][r] = mnew[r];
                rsum[r] = 0.f;
            }
#pragma unroll
            for (int nt = 0; nt < 8; ++nt)
#pragma unroll
                for (int r = 0; r < 4; ++r) {
                    float p = exp2f(sacc[nt][r] - mnew[r]);
                    rsum[r] += p;
                    Ps[wave][(g * 4 + r) * 136 + nt * 16 + c] = f2bf(p);
                }
#pragma unroll
            for (int r = 0; r < 4; ++r) {
#pragma unroll
                for (int mk = 1; mk <= 8; mk <<= 1)
                    rsum[r] += __shfl_xor(rsum[r], mk);
                l_i[ss][r] = l_i[ss][r] * alpha[r] + rsum[r];
            }
#pragma unroll
            for (int nt = 0; nt < 4; ++nt)
#pragma unroll
                for (int r = 0; r < 4; ++r)
                    o_acc[ss][nt][r] *= alpha[r];

#pragma unroll
            for (int ks = 0; ks < 4; ++ks) {
                short8 pf = *(const short8*)&Ps[wave][c * 136 + ks * 32 + g * 8];
#pragma unroll
                for (int nt = 0; nt < 4; ++nt) {
                    short8 vf = *(const short8*)&Vs[(nt * 16 + c) * 136 + ks * 32 + g * 8];
                    o_acc[ss][nt] = __builtin_amdgcn_mfma_f32_16x16x32_bf16(pf, vf, o_acc[ss][nt], 0, 0, 0);
                }
            }
        }
    }

    // epilogue: O / l -> a[b][s][h*64+d] (bf16)
#pragma unroll
    for (int ss = 0; ss < 2; ++ss) {
        float inv[4];
#pragma unroll
        for (int r = 0; r < 4; ++r) inv[r] = 1.0f / l_i[ss][r];
#pragma unroll
        for (int nt = 0; nt < 4; ++nt)
#pragma unroll
            for (int r = 0; r < 4; ++r) {
                int q = q0 + (wave * 2 + ss) * 16 + g * 4 + r;
                aout[(size_t)(b * 2048 + q) * 1024 + h * 64 + nt * 16 + c] =
                    f2bf(o_acc[ss][nt][r] * inv[r]);
            }
    }
}

// ---------------- proj GEMM: [8192,1024]@[1024,1024]^T + bias -> fp32 ----------------
__global__ __launch_bounds__(256) void gemm_proj_kernel(const ushort_t* __restrict__ A,
                                                        const ushort_t* __restrict__ Bt,
                                                        const float* __restrict__ bias,
                                                        float* __restrict__ Cout) {
    const int K = 1024, N = 1024, nbn = 8;
    __shared__ __align__(16) ushort_t As[128 * 32];
    __shared__ __align__(16) ushort_t Bs[128 * 32];
    int bm = blockIdx.x / nbn, bn = blockIdx.x % nbn;
    int m0 = bm << 7, n0 = bn << 7;
    int tid = threadIdx.x;
    int wave = tid >> 6, lane = tid & 63;
    int c = lane & 15, g = lane >> 4;
    int m_off = (wave & 1) << 6, n_off = (wave >> 1) << 6;
    int ldrow = lane >> 2;
    int ldk   = (lane & 3) << 3;

    floatx4 acc[4][4];
#pragma unroll
    for (int mi = 0; mi < 4; ++mi)
#pragma unroll
        for (int ni = 0; ni < 4; ++ni) {
            floatx4 z = {0.f, 0.f, 0.f, 0.f};
            acc[mi][ni] = z;
        }

    for (int kk = 0; kk < K; kk += 32) {
        __syncthreads();
#pragma unroll
        for (int j = 0; j < 2; ++j) {
            int chunk = wave * 2 + j;
            async_ld16(A  + (size_t)(m0 + chunk * 16 + ldrow) * K + kk + ldk, &As[chunk * 512]);
            async_ld16(Bt + (size_t)(n0 + chunk * 16 + ldrow) * K + kk + ldk, &Bs[chunk * 512]);
        }
        __syncthreads();
        short8 bf[4];
#pragma unroll
        for (int ni = 0; ni < 4; ++ni)
            bf[ni] = *(const short8*)&Bs[(n_off + ni * 16 + c) * 32 + g * 8];
#pragma unroll
        for (int mi = 0; mi < 4; ++mi) {
            short8 af = *(const short8*)&As[(m_off + mi * 16 + c) * 32 + g * 8];
#pragma unroll
            for (int ni = 0; ni < 4; ++ni)
                acc[mi][ni] = __builtin_amdgcn_mfma_f32_16x16x32_bf16(af, bf[ni], acc[mi][ni], 0, 0, 0);
        }
    }

    float bv[4];
#pragma unroll
    for (int ni = 0; ni < 4; ++ni) bv[ni] = bias[n0 + n_off + ni * 16 + c];
#pragma unroll
    for (int mi = 0; mi < 4; ++mi)
#pragma unroll
        for (int ni = 0; ni < 4; ++ni)
#pragma unroll
            for (int r = 0; r < 4; ++r) {
                int row = m0 + m_off + mi * 16 + g * 4 + r;
                int col = n0 + n_off + ni * 16 + c;
                Cout[(size_t)row * N + col] = acc[mi][ni][r] + bv[ni];
            }
}

extern "C" void kernel_launch(void* const* d_in, const int* in_sizes, int n_in,
                              void* d_out, int out_size, void* d_ws, size_t ws_size,
                              hipStream_t stream) {
    const float* x        = (const float*)d_in[0];
    const float* c_attn_w = (const float*)d_in[1];
    const float* c_attn_b = (const float*)d_in[2];
    const float* c_proj_w = (const float*)d_in[3];
    const float* c_proj_b = (const float*)d_in[4];
    float* out = (float*)d_out;

    char* ws = (char*)d_ws;
    ushort_t* xb     = (ushort_t*)(ws);              // 16 MB; reused as attn output 'a'
    ushort_t* wqkvT  = (ushort_t*)(ws + 16777216);   // 6 MB
    ushort_t* wprojT = (ushort_t*)(ws + 23068672);   // 2 MB
    ushort_t* qbuf   = (ushort_t*)(ws + 25165824);   // 16 MB  [bh][s][64]
    ushort_t* kbuf   = (ushort_t*)(ws + 41943040);   // 16 MB  [bh][s][64]
    ushort_t* vtbuf  = (ushort_t*)(ws + 58720256);   // 16 MB  [bh][64][2048]

    cvt_bf16_kernel<<<8192, 256, 0, stream>>>(x, xb, 2097152);
    transpose_cvt_kernel<<<32 * 96, 256, 0, stream>>>(c_attn_w, wqkvT, 1024, 3072);
    transpose_cvt_kernel<<<32 * 32, 256, 0, stream>>>(c_proj_w, wprojT, 1024, 1024);
    gemm_qkv_kernel<<<64 * 24, 256, 0, stream>>>(xb, wqkvT, c_attn_b, qbuf, kbuf, vtbuf);
    attn_kernel<<<1024, 256, 0, stream>>>(qbuf, kbuf, vtbuf, xb);
    gemm_proj_kernel<<<64 * 8, 256, 0, stream>>>(xb, wprojT, c_proj_b, out);
}

// Round 3
// 321.112 us; speedup vs baseline: 1.5699x; 1.2643x over previous
//
#include <hip/hip_runtime.h>

typedef unsigned short ushort_t;
typedef __attribute__((ext_vector_type(8))) short short8;
typedef __attribute__((ext_vector_type(4))) float floatx4;

#define LOG2E 1.4426950408889634f

__device__ __forceinline__ unsigned short f2bf(float f) {
    unsigned u = __float_as_uint(f);
    u += 0x7FFF + ((u >> 16) & 1);   // RNE
    return (unsigned short)(u >> 16);
}

__device__ __forceinline__ void async_ld16(const void* gptr, void* lptr) {
    typedef const __attribute__((address_space(1))) unsigned int TG;
    typedef __attribute__((address_space(3))) unsigned int TL;
    __builtin_amdgcn_global_load_lds((TG*)(unsigned long long)gptr,
                                     (TL*)(unsigned)(unsigned long long)lptr,
                                     16, 0, 0);
}

// ---------------- fp32 -> bf16 convert (vec4) ----------------
__global__ __launch_bounds__(256) void cvt_bf16_kernel(const float* __restrict__ in,
                                                       ushort_t* __restrict__ out, int n4) {
    int i = blockIdx.x * 256 + threadIdx.x;
    if (i >= n4) return;
    float4 v = ((const float4*)in)[i];
    unsigned long long r = (unsigned long long)f2bf(v.x)
                         | ((unsigned long long)f2bf(v.y) << 16)
                         | ((unsigned long long)f2bf(v.z) << 32)
                         | ((unsigned long long)f2bf(v.w) << 48);
    ((unsigned long long*)out)[i] = r;
}

// ---------------- fp32 [R][C] -> bf16 [C][R] (weights to B^T) ----------------
__global__ __launch_bounds__(256) void transpose_cvt_kernel(const float* __restrict__ in,
                                                            ushort_t* __restrict__ out,
                                                            int R, int C) {
    __shared__ float t[32][33];
    int nbc = C >> 5;
    int bc = blockIdx.x % nbc, br = blockIdx.x / nbc;
    int tx = threadIdx.x & 31, ty = threadIdx.x >> 5;   // 32 x 8
    int r0 = br << 5, c0 = bc << 5;
#pragma unroll
    for (int j = 0; j < 4; ++j)
        t[ty + j * 8][tx] = in[(size_t)(r0 + ty + j * 8) * C + c0 + tx];
    __syncthreads();
#pragma unroll
    for (int j = 0; j < 4; ++j)
        out[(size_t)(c0 + ty + j * 8) * R + r0 + tx] = f2bf(t[tx][ty + j * 8]);
}

// ---------------- QKV GEMM: [8192,1024]@[1024,3072]^T + bias -> split Q/K/Vt ----------------
// Q,K: [bh][s][64] bf16 ; Vt: [bh][64][2048] bf16
__global__ __launch_bounds__(256) void gemm_qkv_kernel(const ushort_t* __restrict__ A,
                                                       const ushort_t* __restrict__ Bt,
                                                       const float* __restrict__ bias,
                                                       ushort_t* __restrict__ qbuf,
                                                       ushort_t* __restrict__ kbuf,
                                                       ushort_t* __restrict__ vtbuf) {
    const int K = 1024, nbn = 24;
    __shared__ __align__(16) ushort_t As[128 * 32];
    __shared__ __align__(16) ushort_t Bs[128 * 32];
    int bm = blockIdx.x / nbn, bn = blockIdx.x % nbn;
    int m0 = bm << 7, n0 = bn << 7;
    int tid = threadIdx.x;
    int wave = tid >> 6, lane = tid & 63;
    int c = lane & 15, g = lane >> 4;
    int m_off = (wave & 1) << 6, n_off = (wave >> 1) << 6;
    int ldrow = lane >> 2;
    int ldk   = (lane & 3) << 3;

    floatx4 acc[4][4];
#pragma unroll
    for (int mi = 0; mi < 4; ++mi)
#pragma unroll
        for (int ni = 0; ni < 4; ++ni) {
            floatx4 z = {0.f, 0.f, 0.f, 0.f};
            acc[mi][ni] = z;
        }

    for (int kk = 0; kk < K; kk += 32) {
        __syncthreads();
#pragma unroll
        for (int j = 0; j < 2; ++j) {
            int chunk = wave * 2 + j;
            async_ld16(A  + (size_t)(m0 + chunk * 16 + ldrow) * K + kk + ldk, &As[chunk * 512]);
            async_ld16(Bt + (size_t)(n0 + chunk * 16 + ldrow) * K + kk + ldk, &Bs[chunk * 512]);
        }
        __syncthreads();
        short8 bf[4];
#pragma unroll
        for (int ni = 0; ni < 4; ++ni)
            bf[ni] = *(const short8*)&Bs[(n_off + ni * 16 + c) * 32 + g * 8];
#pragma unroll
        for (int mi = 0; mi < 4; ++mi) {
            short8 af = *(const short8*)&As[(m_off + mi * 16 + c) * 32 + g * 8];
#pragma unroll
            for (int ni = 0; ni < 4; ++ni)
                acc[mi][ni] = __builtin_amdgcn_mfma_f32_16x16x32_bf16(af, bf[ni], acc[mi][ni], 0, 0, 0);
        }
    }

    int sec = n0 >> 10;               // 0=Q 1=K 2=V (block-uniform; 1024%128==0)
    float bv[4]; int hh[4], dd[4];
#pragma unroll
    for (int ni = 0; ni < 4; ++ni) {
        int coln = n0 + n_off + ni * 16 + c;
        bv[ni] = bias[coln];
        int coll = coln & 1023;
        hh[ni] = coll >> 6; dd[ni] = coll & 63;
    }
#pragma unroll
    for (int mi = 0; mi < 4; ++mi) {
        int rowb = m0 + m_off + mi * 16 + g * 4;     // +r
        int bb = rowb >> 11, sbase = rowb & 2047;
#pragma unroll
        for (int ni = 0; ni < 4; ++ni) {
            size_t bhn = (size_t)(bb * 16 + hh[ni]);
            if (sec == 2) {
                unsigned long long pk = 0;
#pragma unroll
                for (int r = 0; r < 4; ++r)
                    pk |= (unsigned long long)f2bf(acc[mi][ni][r] + bv[ni]) << (16 * r);
                *(unsigned long long*)(vtbuf + bhn * 131072 + (size_t)dd[ni] * 2048 + sbase) = pk;
            } else {
                ushort_t* dst = (sec == 0 ? qbuf : kbuf) + (bhn * 2048 + sbase) * 64 + dd[ni];
#pragma unroll
                for (int r = 0; r < 4; ++r)
                    dst[r * 64] = f2bf(acc[mi][ni][r] + bv[ni]);
            }
        }
    }
}

// ---------------- flash attention: 1 block = (b,h) x 128 q-rows ----------------
// LPT dispatch (longest blocks first) + prefetch issued AFTER the barrier so
// the vmcnt(0) drain at the NEXT barrier lands after a full compute phase.
__global__ __launch_bounds__(256) void attn_kernel(const ushort_t* __restrict__ qb_,
                                                   const ushort_t* __restrict__ kb_,
                                                   const ushort_t* __restrict__ vtb_,
                                                   ushort_t* __restrict__ aout) {
    __shared__ __align__(16) ushort_t Ks[128 * 72];      // [kp][d] pad 72
    __shared__ __align__(16) ushort_t Vs[64 * 136];      // [d][kp] pad 136
    __shared__ __align__(16) ushort_t Ps[4][16 * 136];   // per-wave P strip
    int bx = blockIdx.x;
    int qb = 15 - (bx >> 6);          // LPT: all qb=15 blocks dispatch first
    int bhix = bx & 63;
    int b = bhix >> 4, h = bhix & 15;
    int q0 = qb << 7;
    int tid = threadIdx.x, wave = tid >> 6, lane = tid & 63;
    int c = lane & 15, g = lane >> 4;
    size_t bh = (size_t)(b * 16 + h);

    const ushort_t* Qp = qb_ + (bh * 2048 + q0) * 64;
    const ushort_t* Kp = kb_ + bh * 131072;
    const ushort_t* Vp = vtb_ + bh * 131072;

    short8 qf[2][2];
#pragma unroll
    for (int ss = 0; ss < 2; ++ss) {
        int qr = (wave * 2 + ss) * 16 + c;
        qf[ss][0] = *(const short8*)(Qp + qr * 64 + g * 8);
        qf[ss][1] = *(const short8*)(Qp + qr * 64 + 32 + g * 8);
    }

    float m_i[2][4], l_i[2][4];
    floatx4 o_acc[2][4];
#pragma unroll
    for (int ss = 0; ss < 2; ++ss)
#pragma unroll
        for (int r = 0; r < 4; ++r) { m_i[ss][r] = -1e30f; l_i[ss][r] = 0.f; }
#pragma unroll
    for (int ss = 0; ss < 2; ++ss)
#pragma unroll
        for (int nt = 0; nt < 4; ++nt) { floatx4 z = {0.f,0.f,0.f,0.f}; o_acc[ss][nt] = z; }

    // prefetch tile 0 into regs
    short8 kreg[4], vreg[4];
#pragma unroll
    for (int it = 0; it < 4; ++it) {
        int idx = it * 256 + tid;
        kreg[it] = *(const short8*)(Kp + idx * 8);
        vreg[it] = *(const short8*)(Vp + (idx >> 4) * 2048 + (idx & 15) * 8);
    }

    const float SC = 0.125f * LOG2E;
    for (int kt = 0; kt <= qb; ++kt) {
        __syncthreads();
#pragma unroll
        for (int it = 0; it < 4; ++it) {
            int idx = it * 256 + tid;
            *(short8*)&Ks[(idx >> 3) * 72 + (idx & 7) * 8] = kreg[it];
            *(short8*)&Vs[(idx >> 4) * 136 + (idx & 15) * 8] = vreg[it];
        }
        __syncthreads();
        // prefetch next tile AFTER the barrier: loads stay in flight across the
        // whole compute phase; drained at next iteration's first barrier.
        if (kt < qb) {
            int s0 = (kt + 1) << 7;
#pragma unroll
            for (int it = 0; it < 4; ++it) {
                int idx = it * 256 + tid;
                kreg[it] = *(const short8*)(Kp + s0 * 64 + idx * 8);
                vreg[it] = *(const short8*)(Vp + (idx >> 4) * 2048 + s0 + (idx & 15) * 8);
            }
        }
        bool diag = (kt == qb);

#pragma unroll
        for (int ss = 0; ss < 2; ++ss) {
            int rl0 = (wave * 2 + ss) * 16;
            floatx4 sacc[8];
#pragma unroll
            for (int nt = 0; nt < 8; ++nt) {
                floatx4 z = {0.f, 0.f, 0.f, 0.f};
                short8 kf0 = *(const short8*)&Ks[(nt * 16 + c) * 72 + g * 8];
                z = __builtin_amdgcn_mfma_f32_16x16x32_bf16(qf[ss][0], kf0, z, 0, 0, 0);
                short8 kf1 = *(const short8*)&Ks[(nt * 16 + c) * 72 + 32 + g * 8];
                sacc[nt] = __builtin_amdgcn_mfma_f32_16x16x32_bf16(qf[ss][1], kf1, z, 0, 0, 0);
            }

            float rmax[4] = {-1e30f, -1e30f, -1e30f, -1e30f};
            if (diag) {
#pragma unroll
                for (int nt = 0; nt < 8; ++nt) {
                    int cl = nt * 16 + c;
#pragma unroll
                    for (int r = 0; r < 4; ++r) {
                        float s = sacc[nt][r] * SC;
                        s = (cl > rl0 + g * 4 + r) ? -1e30f : s;
                        sacc[nt][r] = s;
                        rmax[r] = fmaxf(rmax[r], s);
                    }
                }
            } else {
#pragma unroll
                for (int nt = 0; nt < 8; ++nt)
#pragma unroll
                    for (int r = 0; r < 4; ++r) {
                        float s = sacc[nt][r] * SC;
                        sacc[nt][r] = s;
                        rmax[r] = fmaxf(rmax[r], s);
                    }
            }
#pragma unroll
            for (int r = 0; r < 4; ++r)
#pragma unroll
                for (int mk = 1; mk <= 8; mk <<= 1)
                    rmax[r] = fmaxf(rmax[r], __shfl_xor(rmax[r], mk));

            float mnew[4], alpha[4], rsum[4];
#pragma unroll
            for (int r = 0; r < 4; ++r) {
                mnew[r] = fmaxf(m_i[ss][r], rmax[r]);
                alpha[r] = exp2f(m_i[ss][r] - mnew[r]);
                m_i[ss][r] = mnew[r];
                rsum[r] = 0.f;
            }
#pragma unroll
            for (int nt = 0; nt < 8; ++nt)
#pragma unroll
                for (int r = 0; r < 4; ++r) {
                    float p = exp2f(sacc[nt][r] - mnew[r]);
                    rsum[r] += p;
                    Ps[wave][(g * 4 + r) * 136 + nt * 16 + c] = f2bf(p);
                }
#pragma unroll
            for (int r = 0; r < 4; ++r) {
#pragma unroll
                for (int mk = 1; mk <= 8; mk <<= 1)
                    rsum[r] += __shfl_xor(rsum[r], mk);
                l_i[ss][r] = l_i[ss][r] * alpha[r] + rsum[r];
            }
#pragma unroll
            for (int nt = 0; nt < 4; ++nt)
#pragma unroll
                for (int r = 0; r < 4; ++r)
                    o_acc[ss][nt][r] *= alpha[r];

#pragma unroll
            for (int ks = 0; ks < 4; ++ks) {
                short8 pf = *(const short8*)&Ps[wave][c * 136 + ks * 32 + g * 8];
#pragma unroll
                for (int nt = 0; nt < 4; ++nt) {
                    short8 vf = *(const short8*)&Vs[(nt * 16 + c) * 136 + ks * 32 + g * 8];
                    o_acc[ss][nt] = __builtin_amdgcn_mfma_f32_16x16x32_bf16(pf, vf, o_acc[ss][nt], 0, 0, 0);
                }
            }
        }
    }

    // epilogue: O / l -> a[b][s][h*64+d] (bf16)
#pragma unroll
    for (int ss = 0; ss < 2; ++ss) {
        float inv[4];
#pragma unroll
        for (int r = 0; r < 4; ++r) inv[r] = 1.0f / l_i[ss][r];
#pragma unroll
        for (int nt = 0; nt < 4; ++nt)
#pragma unroll
            for (int r = 0; r < 4; ++r) {
                int q = q0 + (wave * 2 + ss) * 16 + g * 4 + r;
                aout[(size_t)(b * 2048 + q) * 1024 + h * 64 + nt * 16 + c] =
                    f2bf(o_acc[ss][nt][r] * inv[r]);
            }
    }
}

// ---------------- proj GEMM: [8192,1024]@[1024,1024]^T + bias -> fp32 ----------------
__global__ __launch_bounds__(256) void gemm_proj_kernel(const ushort_t* __restrict__ A,
                                                        const ushort_t* __restrict__ Bt,
                                                        const float* __restrict__ bias,
                                                        float* __restrict__ Cout) {
    const int K = 1024, N = 1024, nbn = 8;
    __shared__ __align__(16) ushort_t As[128 * 32];
    __shared__ __align__(16) ushort_t Bs[128 * 32];
    int bm = blockIdx.x / nbn, bn = blockIdx.x % nbn;
    int m0 = bm << 7, n0 = bn << 7;
    int tid = threadIdx.x;
    int wave = tid >> 6, lane = tid & 63;
    int c = lane & 15, g = lane >> 4;
    int m_off = (wave & 1) << 6, n_off = (wave >> 1) << 6;
    int ldrow = lane >> 2;
    int ldk   = (lane & 3) << 3;

    floatx4 acc[4][4];
#pragma unroll
    for (int mi = 0; mi < 4; ++mi)
#pragma unroll
        for (int ni = 0; ni < 4; ++ni) {
            floatx4 z = {0.f, 0.f, 0.f, 0.f};
            acc[mi][ni] = z;
        }

    for (int kk = 0; kk < K; kk += 32) {
        __syncthreads();
#pragma unroll
        for (int j = 0; j < 2; ++j) {
            int chunk = wave * 2 + j;
            async_ld16(A  + (size_t)(m0 + chunk * 16 + ldrow) * K + kk + ldk, &As[chunk * 512]);
            async_ld16(Bt + (size_t)(n0 + chunk * 16 + ldrow) * K + kk + ldk, &Bs[chunk * 512]);
        }
        __syncthreads();
        short8 bf[4];
#pragma unroll
        for (int ni = 0; ni < 4; ++ni)
            bf[ni] = *(const short8*)&Bs[(n_off + ni * 16 + c) * 32 + g * 8];
#pragma unroll
        for (int mi = 0; mi < 4; ++mi) {
            short8 af = *(const short8*)&As[(m_off + mi * 16 + c) * 32 + g * 8];
#pragma unroll
            for (int ni = 0; ni < 4; ++ni)
                acc[mi][ni] = __builtin_amdgcn_mfma_f32_16x16x32_bf16(af, bf[ni], acc[mi][ni], 0, 0, 0);
        }
    }

    float bv[4];
#pragma unroll
    for (int ni = 0; ni < 4; ++ni) bv[ni] = bias[n0 + n_off + ni * 16 + c];
#pragma unroll
    for (int mi = 0; mi < 4; ++mi)
#pragma unroll
        for (int ni = 0; ni < 4; ++ni)
#pragma unroll
            for (int r = 0; r < 4; ++r) {
                int row = m0 + m_off + mi * 16 + g * 4 + r;
                int col = n0 + n_off + ni * 16 + c;
                Cout[(size_t)row * N + col] = acc[mi][ni][r] + bv[ni];
            }
}

extern "C" void kernel_launch(void* const* d_in, const int* in_sizes, int n_in,
                              void* d_out, int out_size, void* d_ws, size_t ws_size,
                              hipStream_t stream) {
    const float* x        = (const float*)d_in[0];
    const float* c_attn_w = (const float*)d_in[1];
    const float* c_attn_b = (const float*)d_in[2];
    const float* c_proj_w = (const float*)d_in[3];
    const float* c_proj_b = (const float*)d_in[4];
    float* out = (float*)d_out;

    char* ws = (char*)d_ws;
    ushort_t* xb     = (ushort_t*)(ws);              // 16 MB; reused as attn output 'a'
    ushort_t* wqkvT  = (ushort_t*)(ws + 16777216);   // 6 MB
    ushort_t* wprojT = (ushort_t*)(ws + 23068672);   // 2 MB
    ushort_t* qbuf   = (ushort_t*)(ws + 25165824);   // 16 MB  [bh][s][64]
    ushort_t* kbuf   = (ushort_t*)(ws + 41943040);   // 16 MB  [bh][s][64]
    ushort_t* vtbuf  = (ushort_t*)(ws + 58720256);   // 16 MB  [bh][64][2048]

    cvt_bf16_kernel<<<8192, 256, 0, stream>>>(x, xb, 2097152);
    transpose_cvt_kernel<<<32 * 96, 256, 0, stream>>>(c_attn_w, wqkvT, 1024, 3072);
    transpose_cvt_kernel<<<32 * 32, 256, 0, stream>>>(c_proj_w, wprojT, 1024, 1024);
    gemm_qkv_kernel<<<64 * 24, 256, 0, stream>>>(xb, wqkvT, c_attn_b, qbuf, kbuf, vtbuf);
    attn_kernel<<<1024, 256, 0, stream>>>(qbuf, kbuf, vtbuf, xb);
    gemm_proj_kernel<<<64 * 8, 256, 0, stream>>>(xb, wprojT, c_proj_b, out);
}

// Round 4
// 296.764 us; speedup vs baseline: 1.6987x; 1.0820x over previous
//
#include <hip/hip_runtime.h>
#include <hip/hip_bf16.h>

typedef unsigned short ushort_t;
typedef __attribute__((ext_vector_type(8))) short short8;
typedef __attribute__((ext_vector_type(4))) float floatx4;

#define LOG2E 1.4426950408889634f

__device__ __forceinline__ unsigned short f2bf(float f) {
    unsigned u = __float_as_uint(f);
    u += 0x7FFF + ((u >> 16) & 1);   // RNE
    return (unsigned short)(u >> 16);
}

__device__ __forceinline__ void async_ld16(const void* gptr, void* lptr) {
    typedef const __attribute__((address_space(1))) unsigned int TG;
    typedef __attribute__((address_space(3))) unsigned int TL;
    __builtin_amdgcn_global_load_lds((TG*)(unsigned long long)gptr,
                                     (TL*)(unsigned)(unsigned long long)lptr,
                                     16, 0, 0);
}

// ---------------- fp32 -> bf16 convert (vec4) ----------------
__global__ __launch_bounds__(256) void cvt_bf16_kernel(const float* __restrict__ in,
                                                       ushort_t* __restrict__ out, int n4) {
    int i = blockIdx.x * 256 + threadIdx.x;
    if (i >= n4) return;
    float4 v = ((const float4*)in)[i];
    unsigned long long r = (unsigned long long)f2bf(v.x)
                         | ((unsigned long long)f2bf(v.y) << 16)
                         | ((unsigned long long)f2bf(v.z) << 32)
                         | ((unsigned long long)f2bf(v.w) << 48);
    ((unsigned long long*)out)[i] = r;
}

// ---------------- fp32 [R][C] -> bf16 [C][R] (weights to B^T) ----------------
__global__ __launch_bounds__(256) void transpose_cvt_kernel(const float* __restrict__ in,
                                                            ushort_t* __restrict__ out,
                                                            int R, int C) {
    __shared__ float t[32][33];
    int nbc = C >> 5;
    int bc = blockIdx.x % nbc, br = blockIdx.x / nbc;
    int tx = threadIdx.x & 31, ty = threadIdx.x >> 5;   // 32 x 8
    int r0 = br << 5, c0 = bc << 5;
#pragma unroll
    for (int j = 0; j < 4; ++j)
        t[ty + j * 8][tx] = in[(size_t)(r0 + ty + j * 8) * C + c0 + tx];
    __syncthreads();
#pragma unroll
    for (int j = 0; j < 4; ++j)
        out[(size_t)(c0 + ty + j * 8) * R + r0 + tx] = f2bf(t[tx][ty + j * 8]);
}

// ---------------- QKV GEMM: [8192,1024]@[1024,3072]^T + bias -> split Q/K/Vt ----------------
// Q,K: [bh][s][64] bf16 ; Vt: [bh][64][2048] bf16
// Q (incl. bias) is pre-scaled by 0.125*log2(e) so attn can use exp2 directly.
__global__ __launch_bounds__(256) void gemm_qkv_kernel(const ushort_t* __restrict__ A,
                                                       const ushort_t* __restrict__ Bt,
                                                       const float* __restrict__ bias,
                                                       ushort_t* __restrict__ qbuf,
                                                       ushort_t* __restrict__ kbuf,
                                                       ushort_t* __restrict__ vtbuf) {
    const int K = 1024, nbn = 24;
    __shared__ __align__(16) ushort_t As[128 * 32];
    __shared__ __align__(16) ushort_t Bs[128 * 32];
    int bm = blockIdx.x / nbn, bn = blockIdx.x % nbn;
    int m0 = bm << 7, n0 = bn << 7;
    int tid = threadIdx.x;
    int wave = tid >> 6, lane = tid & 63;
    int c = lane & 15, g = lane >> 4;
    int m_off = (wave & 1) << 6, n_off = (wave >> 1) << 6;
    int ldrow = lane >> 2;
    int ldk   = (lane & 3) << 3;

    floatx4 acc[4][4];
#pragma unroll
    for (int mi = 0; mi < 4; ++mi)
#pragma unroll
        for (int ni = 0; ni < 4; ++ni) {
            floatx4 z = {0.f, 0.f, 0.f, 0.f};
            acc[mi][ni] = z;
        }

    for (int kk = 0; kk < K; kk += 32) {
        __syncthreads();
#pragma unroll
        for (int j = 0; j < 2; ++j) {
            int chunk = wave * 2 + j;
            async_ld16(A  + (size_t)(m0 + chunk * 16 + ldrow) * K + kk + ldk, &As[chunk * 512]);
            async_ld16(Bt + (size_t)(n0 + chunk * 16 + ldrow) * K + kk + ldk, &Bs[chunk * 512]);
        }
        __syncthreads();
        short8 bf[4];
#pragma unroll
        for (int ni = 0; ni < 4; ++ni)
            bf[ni] = *(const short8*)&Bs[(n_off + ni * 16 + c) * 32 + g * 8];
#pragma unroll
        for (int mi = 0; mi < 4; ++mi) {
            short8 af = *(const short8*)&As[(m_off + mi * 16 + c) * 32 + g * 8];
#pragma unroll
            for (int ni = 0; ni < 4; ++ni)
                acc[mi][ni] = __builtin_amdgcn_mfma_f32_16x16x32_bf16(af, bf[ni], acc[mi][ni], 0, 0, 0);
        }
    }

    int sec = n0 >> 10;               // 0=Q 1=K 2=V (block-uniform; 1024%128==0)
    float scl = (sec == 0) ? (0.125f * LOG2E) : 1.0f;
    float bv[4]; int hh[4], dd[4];
#pragma unroll
    for (int ni = 0; ni < 4; ++ni) {
        int coln = n0 + n_off + ni * 16 + c;
        bv[ni] = bias[coln];
        int coll = coln & 1023;
        hh[ni] = coll >> 6; dd[ni] = coll & 63;
    }
#pragma unroll
    for (int mi = 0; mi < 4; ++mi) {
        int rowb = m0 + m_off + mi * 16 + g * 4;     // +r
        int bb = rowb >> 11, sbase = rowb & 2047;
#pragma unroll
        for (int ni = 0; ni < 4; ++ni) {
            size_t bhn = (size_t)(bb * 16 + hh[ni]);
            if (sec == 2) {
                unsigned long long pk = 0;
#pragma unroll
                for (int r = 0; r < 4; ++r)
                    pk |= (unsigned long long)f2bf(acc[mi][ni][r] + bv[ni]) << (16 * r);
                *(unsigned long long*)(vtbuf + bhn * 131072 + (size_t)dd[ni] * 2048 + sbase) = pk;
            } else {
                ushort_t* dst = (sec == 0 ? qbuf : kbuf) + (bhn * 2048 + sbase) * 64 + dd[ni];
#pragma unroll
                for (int r = 0; r < 4; ++r)
                    dst[r * 64] = f2bf((acc[mi][ni][r] + bv[ni]) * scl);
            }
        }
    }
}

// ---------------- flash attention: 1 block = (b,h) x 128 q-rows ----------------
// Transposed-softmax: S^T = K·Q^T so each lane owns one q-row -> serial row
// reductions (no shuffles), b64 P^T stores, no online max (logits bounded),
// deferred l-reduction. LPT dispatch + post-barrier register prefetch.
__global__ __launch_bounds__(256) void attn_kernel(const ushort_t* __restrict__ qb_,
                                                   const ushort_t* __restrict__ kb_,
                                                   const ushort_t* __restrict__ vtb_,
                                                   ushort_t* __restrict__ aout) {
    __shared__ __align__(16) ushort_t Ks[128 * 72];      // [kp][d] pad 72
    __shared__ __align__(16) ushort_t Vs[64 * 136];      // [d][kp] pad 136
    __shared__ __align__(16) ushort_t Ps[4][16 * 136];   // per-wave P[q][kp] strip
    int bx = blockIdx.x;
    int qb = 15 - (bx >> 6);          // LPT: all qb=15 blocks dispatch first
    int bhix = bx & 63;
    int b = bhix >> 4, h = bhix & 15;
    int q0 = qb << 7;
    int tid = threadIdx.x, wave = tid >> 6, lane = tid & 63;
    int c = lane & 15, g = lane >> 4;
    size_t bh = (size_t)(b * 16 + h);

    const ushort_t* Qp = qb_ + (bh * 2048 + q0) * 64;
    const ushort_t* Kp = kb_ + bh * 131072;
    const ushort_t* Vp = vtb_ + bh * 131072;

    short8 qf[2][2];
#pragma unroll
    for (int ss = 0; ss < 2; ++ss) {
        int qr = (wave * 2 + ss) * 16 + c;
        qf[ss][0] = *(const short8*)(Qp + qr * 64 + g * 8);
        qf[ss][1] = *(const short8*)(Qp + qr * 64 + 32 + g * 8);
    }

    float l_part[2] = {0.f, 0.f};     // per-lane partial sum for q = rl0 + c
    floatx4 o_acc[2][4];
#pragma unroll
    for (int ss = 0; ss < 2; ++ss)
#pragma unroll
        for (int nt = 0; nt < 4; ++nt) { floatx4 z = {0.f,0.f,0.f,0.f}; o_acc[ss][nt] = z; }

    // prefetch tile 0 into regs
    short8 kreg[4], vreg[4];
#pragma unroll
    for (int it = 0; it < 4; ++it) {
        int idx = it * 256 + tid;
        kreg[it] = *(const short8*)(Kp + idx * 8);
        vreg[it] = *(const short8*)(Vp + (idx >> 4) * 2048 + (idx & 15) * 8);
    }

    for (int kt = 0; kt <= qb; ++kt) {
        int kt0 = kt << 7;
        __syncthreads();
#pragma unroll
        for (int it = 0; it < 4; ++it) {
            int idx = it * 256 + tid;
            *(short8*)&Ks[(idx >> 3) * 72 + (idx & 7) * 8] = kreg[it];
            *(short8*)&Vs[(idx >> 4) * 136 + (idx & 15) * 8] = vreg[it];
        }
        __syncthreads();
        // prefetch next tile AFTER the barrier: loads stay in flight across the
        // whole compute phase; drained at next iteration's first barrier.
        if (kt < qb) {
            int s0 = (kt + 1) << 7;
#pragma unroll
            for (int it = 0; it < 4; ++it) {
                int idx = it * 256 + tid;
                kreg[it] = *(const short8*)(Kp + s0 * 64 + idx * 8);
                vreg[it] = *(const short8*)(Vp + (idx >> 4) * 2048 + s0 + (idx & 15) * 8);
            }
        }
        bool diag = (kt == qb);

#pragma unroll
        for (int ss = 0; ss < 2; ++ss) {
            int rl0 = (wave * 2 + ss) * 16;
            // S^T = K·Q^T : A = K-tile (m = kp), B = Q^T (n = q).
            // D[m=kp][n=q]: lane holds q = rl0+c, kp = kt0 + nt*16 + g*4 + r.
            floatx4 sacc[8];
#pragma unroll
            for (int nt = 0; nt < 8; ++nt) {
                floatx4 z = {0.f, 0.f, 0.f, 0.f};
                short8 kf0 = *(const short8*)&Ks[(nt * 16 + c) * 72 + g * 8];
                z = __builtin_amdgcn_mfma_f32_16x16x32_bf16(kf0, qf[ss][0], z, 0, 0, 0);
                short8 kf1 = *(const short8*)&Ks[(nt * 16 + c) * 72 + 32 + g * 8];
                sacc[nt] = __builtin_amdgcn_mfma_f32_16x16x32_bf16(kf1, qf[ss][1], z, 0, 0, 0);
            }

            int qg = q0 + rl0 + c;     // this lane's q row
            float lp = 0.f;
#pragma unroll
            for (int nt = 0; nt < 8; ++nt) {
                float p[4];
#pragma unroll
                for (int r = 0; r < 4; ++r) {
                    float s = sacc[nt][r];
                    if (diag) {
                        int kp = kt0 + nt * 16 + g * 4 + r;
                        s = (kp > qg) ? -1e30f : s;
                    }
                    p[r] = exp2f(s);          // Q pre-scaled by 0.125*log2e
                    lp += p[r];
                }
                union { unsigned long long u; __hip_bfloat162 h[2]; } pk;
                pk.h[0] = __float22bfloat162_rn(make_float2(p[0], p[1]));
                pk.h[1] = __float22bfloat162_rn(make_float2(p[2], p[3]));
                *(unsigned long long*)&Ps[wave][c * 136 + nt * 16 + g * 4] = pk.u;
            }
            l_part[ss] += lp;

            // O += P @ V   (A = P[q][kp] from LDS, B = V via Vs[d][kp])
#pragma unroll
            for (int ks = 0; ks < 4; ++ks) {
                short8 pf = *(const short8*)&Ps[wave][c * 136 + ks * 32 + g * 8];
#pragma unroll
                for (int nt = 0; nt < 4; ++nt) {
                    short8 vf = *(const short8*)&Vs[(nt * 16 + c) * 136 + ks * 32 + g * 8];
                    o_acc[ss][nt] = __builtin_amdgcn_mfma_f32_16x16x32_bf16(pf, vf, o_acc[ss][nt], 0, 0, 0);
                }
            }
        }
    }

    // epilogue: reduce l across g-groups, broadcast, O/l -> a[b][s][h*64+d]
#pragma unroll
    for (int ss = 0; ss < 2; ++ss) {
        float l = l_part[ss];
        l += __shfl_xor(l, 16);
        l += __shfl_xor(l, 32);
        float linv = 1.0f / l;         // lane {c,c+16,c+32,c+48} hold l for q=rl0+c
        float inv[4];
#pragma unroll
        for (int r = 0; r < 4; ++r)
            inv[r] = __shfl(linv, g * 4 + r);   // q-in-strip = g*4+r lives at lane g*4+r
#pragma unroll
        for (int nt = 0; nt < 4; ++nt)
#pragma unroll
            for (int r = 0; r < 4; ++r) {
                int q = q0 + (wave * 2 + ss) * 16 + g * 4 + r;
                aout[(size_t)(b * 2048 + q) * 1024 + h * 64 + nt * 16 + c] =
                    f2bf(o_acc[ss][nt][r] * inv[r]);
            }
    }
}

// ---------------- proj GEMM: [8192,1024]@[1024,1024]^T + bias -> fp32 ----------------
__global__ __launch_bounds__(256) void gemm_proj_kernel(const ushort_t* __restrict__ A,
                                                        const ushort_t* __restrict__ Bt,
                                                        const float* __restrict__ bias,
                                                        float* __restrict__ Cout) {
    const int K = 1024, N = 1024, nbn = 8;
    __shared__ __align__(16) ushort_t As[128 * 32];
    __shared__ __align__(16) ushort_t Bs[128 * 32];
    int bm = blockIdx.x / nbn, bn = blockIdx.x % nbn;
    int m0 = bm << 7, n0 = bn << 7;
    int tid = threadIdx.x;
    int wave = tid >> 6, lane = tid & 63;
    int c = lane & 15, g = lane >> 4;
    int m_off = (wave & 1) << 6, n_off = (wave >> 1) << 6;
    int ldrow = lane >> 2;
    int ldk   = (lane & 3) << 3;

    floatx4 acc[4][4];
#pragma unroll
    for (int mi = 0; mi < 4; ++mi)
#pragma unroll
        for (int ni = 0; ni < 4; ++ni) {
            floatx4 z = {0.f, 0.f, 0.f, 0.f};
            acc[mi][ni] = z;
        }

    for (int kk = 0; kk < K; kk += 32) {
        __syncthreads();
#pragma unroll
        for (int j = 0; j < 2; ++j) {
            int chunk = wave * 2 + j;
            async_ld16(A  + (size_t)(m0 + chunk * 16 + ldrow) * K + kk + ldk, &As[chunk * 512]);
            async_ld16(Bt + (size_t)(n0 + chunk * 16 + ldrow) * K + kk + ldk, &Bs[chunk * 512]);
        }
        __syncthreads();
        short8 bf[4];
#pragma unroll
        for (int ni = 0; ni < 4; ++ni)
            bf[ni] = *(const short8*)&Bs[(n_off + ni * 16 + c) * 32 + g * 8];
#pragma unroll
        for (int mi = 0; mi < 4; ++mi) {
            short8 af = *(const short8*)&As[(m_off + mi * 16 + c) * 32 + g * 8];
#pragma unroll
            for (int ni = 0; ni < 4; ++ni)
                acc[mi][ni] = __builtin_amdgcn_mfma_f32_16x16x32_bf16(af, bf[ni], acc[mi][ni], 0, 0, 0);
        }
    }

    float bv[4];
#pragma unroll
    for (int ni = 0; ni < 4; ++ni) bv[ni] = bias[n0 + n_off + ni * 16 + c];
#pragma unroll
    for (int mi = 0; mi < 4; ++mi)
#pragma unroll
        for (int ni = 0; ni < 4; ++ni)
#pragma unroll
            for (int r = 0; r < 4; ++r) {
                int row = m0 + m_off + mi * 16 + g * 4 + r;
                int col = n0 + n_off + ni * 16 + c;
                Cout[(size_t)row * N + col] = acc[mi][ni][r] + bv[ni];
            }
}

extern "C" void kernel_launch(void* const* d_in, const int* in_sizes, int n_in,
                              void* d_out, int out_size, void* d_ws, size_t ws_size,
                              hipStream_t stream) {
    const float* x        = (const float*)d_in[0];
    const float* c_attn_w = (const float*)d_in[1];
    const float* c_attn_b = (const float*)d_in[2];
    const float* c_proj_w = (const float*)d_in[3];
    const float* c_proj_b = (const float*)d_in[4];
    float* out = (float*)d_out;

    char* ws = (char*)d_ws;
    ushort_t* xb     = (ushort_t*)(ws);              // 16 MB; reused as attn output 'a'
    ushort_t* wqkvT  = (ushort_t*)(ws + 16777216);   // 6 MB
    ushort_t* wprojT = (ushort_t*)(ws + 23068672);   // 2 MB
    ushort_t* qbuf   = (ushort_t*)(ws + 25165824);   // 16 MB  [bh][s][64]  (pre-scaled)
    ushort_t* kbuf   = (ushort_t*)(ws + 41943040);   // 16 MB  [bh][s][64]
    ushort_t* vtbuf  = (ushort_t*)(ws + 58720256);   // 16 MB  [bh][64][2048]

    cvt_bf16_kernel<<<8192, 256, 0, stream>>>(x, xb, 2097152);
    transpose_cvt_kernel<<<32 * 96, 256, 0, stream>>>(c_attn_w, wqkvT, 1024, 3072);
    transpose_cvt_kernel<<<32 * 32, 256, 0, stream>>>(c_proj_w, wprojT, 1024, 1024);
    gemm_qkv_kernel<<<64 * 24, 256, 0, stream>>>(xb, wqkvT, c_attn_b, qbuf, kbuf, vtbuf);
    attn_kernel<<<1024, 256, 0, stream>>>(qbuf, kbuf, vtbuf, xb);
    gemm_proj_kernel<<<64 * 8, 256, 0, stream>>>(xb, wprojT, c_proj_b, out);
}

// Round 5
// 292.265 us; speedup vs baseline: 1.7249x; 1.0154x over previous
//
#include <hip/hip_runtime.h>
#include <hip/hip_bf16.h>

typedef unsigned short ushort_t;
typedef __attribute__((ext_vector_type(8))) short short8;
typedef __attribute__((ext_vector_type(4))) float floatx4;

#define LOG2E 1.4426950408889634f

__device__ __forceinline__ unsigned short f2bf(float f) {
    unsigned u = __float_as_uint(f);
    u += 0x7FFF + ((u >> 16) & 1);   // RNE
    return (unsigned short)(u >> 16);
}

__device__ __forceinline__ void async_ld16(const void* gptr, void* lptr) {
    typedef const __attribute__((address_space(1))) unsigned int TG;
    typedef __attribute__((address_space(3))) unsigned int TL;
    __builtin_amdgcn_global_load_lds((TG*)(unsigned long long)gptr,
                                     (TL*)(unsigned)(unsigned long long)lptr,
                                     16, 0, 0);
}

// ---------------- fused prep: x->bf16 | w_qkv transpose | w_proj transpose ----------------
__global__ __launch_bounds__(256) void prep_kernel(const float* __restrict__ x,
                                                   const float* __restrict__ wqkv,
                                                   const float* __restrict__ wproj,
                                                   ushort_t* __restrict__ xb,
                                                   ushort_t* __restrict__ wqkvT,
                                                   ushort_t* __restrict__ wprojT) {
    __shared__ float t[32][33];
    int bx = blockIdx.x;
    if (bx < 8192) {
        int i = bx * 256 + threadIdx.x;
        float4 v = ((const float4*)x)[i];
        unsigned long long r = (unsigned long long)f2bf(v.x)
                             | ((unsigned long long)f2bf(v.y) << 16)
                             | ((unsigned long long)f2bf(v.z) << 32)
                             | ((unsigned long long)f2bf(v.w) << 48);
        ((unsigned long long*)xb)[i] = r;
        return;
    }
    const float* in; ushort_t* out; int R, C, bidx;
    if (bx < 8192 + 3072) { in = wqkv; out = wqkvT; R = 1024; C = 3072; bidx = bx - 8192; }
    else                  { in = wproj; out = wprojT; R = 1024; C = 1024; bidx = bx - 11264; }
    int nbc = C >> 5;
    int bc = bidx % nbc, br = bidx / nbc;
    int tx = threadIdx.x & 31, ty = threadIdx.x >> 5;   // 32 x 8
    int r0 = br << 5, c0 = bc << 5;
#pragma unroll
    for (int j = 0; j < 4; ++j)
        t[ty + j * 8][tx] = in[(size_t)(r0 + ty + j * 8) * C + c0 + tx];
    __syncthreads();
#pragma unroll
    for (int j = 0; j < 4; ++j)
        out[(size_t)(c0 + ty + j * 8) * R + r0 + tx] = f2bf(t[tx][ty + j * 8]);
}

// ---------------- QKV GEMM: [8192,1024]@[1024,3072]^T + bias -> split Q/K/Vt ----------------
// Q,K: [bh][s][64] bf16 ; Vt: [bh][64][2048] bf16
// Q (incl. bias) is pre-scaled by 0.125*log2(e) so attn can use exp2 directly.
__global__ __launch_bounds__(256) void gemm_qkv_kernel(const ushort_t* __restrict__ A,
                                                       const ushort_t* __restrict__ Bt,
                                                       const float* __restrict__ bias,
                                                       ushort_t* __restrict__ qbuf,
                                                       ushort_t* __restrict__ kbuf,
                                                       ushort_t* __restrict__ vtbuf) {
    const int K = 1024, nbn = 24;
    __shared__ __align__(16) ushort_t As[128 * 32];
    __shared__ __align__(16) ushort_t Bs[128 * 32];
    int bm = blockIdx.x / nbn, bn = blockIdx.x % nbn;
    int m0 = bm << 7, n0 = bn << 7;
    int tid = threadIdx.x;
    int wave = tid >> 6, lane = tid & 63;
    int c = lane & 15, g = lane >> 4;
    int m_off = (wave & 1) << 6, n_off = (wave >> 1) << 6;
    int ldrow = lane >> 2;
    int ldk   = (lane & 3) << 3;

    floatx4 acc[4][4];
#pragma unroll
    for (int mi = 0; mi < 4; ++mi)
#pragma unroll
        for (int ni = 0; ni < 4; ++ni) {
            floatx4 z = {0.f, 0.f, 0.f, 0.f};
            acc[mi][ni] = z;
        }

    for (int kk = 0; kk < K; kk += 32) {
        __syncthreads();
#pragma unroll
        for (int j = 0; j < 2; ++j) {
            int chunk = wave * 2 + j;
            async_ld16(A  + (size_t)(m0 + chunk * 16 + ldrow) * K + kk + ldk, &As[chunk * 512]);
            async_ld16(Bt + (size_t)(n0 + chunk * 16 + ldrow) * K + kk + ldk, &Bs[chunk * 512]);
        }
        __syncthreads();
        short8 bf[4];
#pragma unroll
        for (int ni = 0; ni < 4; ++ni)
            bf[ni] = *(const short8*)&Bs[(n_off + ni * 16 + c) * 32 + g * 8];
#pragma unroll
        for (int mi = 0; mi < 4; ++mi) {
            short8 af = *(const short8*)&As[(m_off + mi * 16 + c) * 32 + g * 8];
#pragma unroll
            for (int ni = 0; ni < 4; ++ni)
                acc[mi][ni] = __builtin_amdgcn_mfma_f32_16x16x32_bf16(af, bf[ni], acc[mi][ni], 0, 0, 0);
        }
    }

    int sec = n0 >> 10;               // 0=Q 1=K 2=V (block-uniform; 1024%128==0)
    float scl = (sec == 0) ? (0.125f * LOG2E) : 1.0f;
    float bv[4]; int hh[4], dd[4];
#pragma unroll
    for (int ni = 0; ni < 4; ++ni) {
        int coln = n0 + n_off + ni * 16 + c;
        bv[ni] = bias[coln];
        int coll = coln & 1023;
        hh[ni] = coll >> 6; dd[ni] = coll & 63;
    }
#pragma unroll
    for (int mi = 0; mi < 4; ++mi) {
        int rowb = m0 + m_off + mi * 16 + g * 4;     // +r
        int bb = rowb >> 11, sbase = rowb & 2047;
#pragma unroll
        for (int ni = 0; ni < 4; ++ni) {
            size_t bhn = (size_t)(bb * 16 + hh[ni]);
            if (sec == 2) {
                unsigned long long pk = 0;
#pragma unroll
                for (int r = 0; r < 4; ++r)
                    pk |= (unsigned long long)f2bf(acc[mi][ni][r] + bv[ni]) << (16 * r);
                *(unsigned long long*)(vtbuf + bhn * 131072 + (size_t)dd[ni] * 2048 + sbase) = pk;
            } else {
                ushort_t* dst = (sec == 0 ? qbuf : kbuf) + (bhn * 2048 + sbase) * 64 + dd[ni];
#pragma unroll
                for (int r = 0; r < 4; ++r)
                    dst[r * 64] = f2bf((acc[mi][ni][r] + bv[ni]) * scl);
            }
        }
    }
}

// ---------------- flash attention: 1 block = (b,h) x 128 q-rows ----------------
// Transposed-softmax (each lane owns one q), no online max (bounded logits),
// kf reads shared across both 16-q strips (interleaved QK), strip-1 P held in
// regs until strip-0 PV finishes. LPT dispatch + post-barrier reg prefetch.
__global__ __launch_bounds__(256) void attn_kernel(const ushort_t* __restrict__ qb_,
                                                   const ushort_t* __restrict__ kb_,
                                                   const ushort_t* __restrict__ vtb_,
                                                   ushort_t* __restrict__ aout) {
    __shared__ __align__(16) ushort_t Ks[128 * 72];      // [kp][d] pad 72
    __shared__ __align__(16) ushort_t Vs[64 * 136];      // [d][kp] pad 136
    __shared__ __align__(16) ushort_t Ps[4][16 * 136];   // per-wave P[q][kp] strip
    int bx = blockIdx.x;
    int qb = 15 - (bx >> 6);          // LPT: all qb=15 blocks dispatch first
    int bhix = bx & 63;
    int b = bhix >> 4, h = bhix & 15;
    int q0 = qb << 7;
    int tid = threadIdx.x, wave = tid >> 6, lane = tid & 63;
    int c = lane & 15, g = lane >> 4;
    size_t bh = (size_t)(b * 16 + h);

    const ushort_t* Qp = qb_ + (bh * 2048 + q0) * 64;
    const ushort_t* Kp = kb_ + bh * 131072;
    const ushort_t* Vp = vtb_ + bh * 131072;

    short8 qf[2][2];
#pragma unroll
    for (int ss = 0; ss < 2; ++ss) {
        int qr = (wave * 2 + ss) * 16 + c;
        qf[ss][0] = *(const short8*)(Qp + qr * 64 + g * 8);
        qf[ss][1] = *(const short8*)(Qp + qr * 64 + 32 + g * 8);
    }

    float l_part[2] = {0.f, 0.f};     // per-lane partial sum for q = rl0 + c
    floatx4 o_acc[2][4];
#pragma unroll
    for (int ss = 0; ss < 2; ++ss)
#pragma unroll
        for (int nt = 0; nt < 4; ++nt) { floatx4 z = {0.f,0.f,0.f,0.f}; o_acc[ss][nt] = z; }

    // prefetch tile 0 into regs
    short8 kreg[4], vreg[4];
#pragma unroll
    for (int it = 0; it < 4; ++it) {
        int idx = it * 256 + tid;
        kreg[it] = *(const short8*)(Kp + idx * 8);
        vreg[it] = *(const short8*)(Vp + (idx >> 4) * 2048 + (idx & 15) * 8);
    }

    int qg0 = q0 + wave * 32 + c;      // strip-0 q row; strip-1 = +16
    for (int kt = 0; kt <= qb; ++kt) {
        int kt0 = kt << 7;
        __syncthreads();
#pragma unroll
        for (int it = 0; it < 4; ++it) {
            int idx = it * 256 + tid;
            *(short8*)&Ks[(idx >> 3) * 72 + (idx & 7) * 8] = kreg[it];
            *(short8*)&Vs[(idx >> 4) * 136 + (idx & 15) * 8] = vreg[it];
        }
        __syncthreads();
        // prefetch next tile AFTER the barrier: loads stay in flight across the
        // whole compute phase; drained at next iteration's first barrier.
        if (kt < qb) {
            int s0 = (kt + 1) << 7;
#pragma unroll
            for (int it = 0; it < 4; ++it) {
                int idx = it * 256 + tid;
                kreg[it] = *(const short8*)(Kp + s0 * 64 + idx * 8);
                vreg[it] = *(const short8*)(Vp + (idx >> 4) * 2048 + s0 + (idx & 15) * 8);
            }
        }
        bool diag = (kt == qb);

        // ---- QK for BOTH strips per kf read; strip0 P -> LDS, strip1 P -> regs
        unsigned pd[8][2];             // strip-1 packed P (bf16x2 dwords)
        float lp0 = 0.f, lp1 = 0.f;
#pragma unroll
        for (int nt = 0; nt < 8; ++nt) {
            short8 kf0 = *(const short8*)&Ks[(nt * 16 + c) * 72 + g * 8];
            short8 kf1 = *(const short8*)&Ks[(nt * 16 + c) * 72 + 32 + g * 8];
            floatx4 z0 = {0.f, 0.f, 0.f, 0.f};
            z0 = __builtin_amdgcn_mfma_f32_16x16x32_bf16(kf0, qf[0][0], z0, 0, 0, 0);
            z0 = __builtin_amdgcn_mfma_f32_16x16x32_bf16(kf1, qf[0][1], z0, 0, 0, 0);
            floatx4 z1 = {0.f, 0.f, 0.f, 0.f};
            z1 = __builtin_amdgcn_mfma_f32_16x16x32_bf16(kf0, qf[1][0], z1, 0, 0, 0);
            z1 = __builtin_amdgcn_mfma_f32_16x16x32_bf16(kf1, qf[1][1], z1, 0, 0, 0);

            int kpb = kt0 + nt * 16 + g * 4;
            float p0[4], p1[4];
#pragma unroll
            for (int r = 0; r < 4; ++r) {
                float s0v = z0[r], s1v = z1[r];
                if (diag) {
                    int kp = kpb + r;
                    s0v = (kp > qg0)      ? -1e30f : s0v;
                    s1v = (kp > qg0 + 16) ? -1e30f : s1v;
                }
                p0[r] = exp2f(s0v); lp0 += p0[r];
                p1[r] = exp2f(s1v); lp1 += p1[r];
            }
            union { unsigned long long u; __hip_bfloat162 h[2]; unsigned w[2]; } pk;
            pk.h[0] = __float22bfloat162_rn(make_float2(p0[0], p0[1]));
            pk.h[1] = __float22bfloat162_rn(make_float2(p0[2], p0[3]));
            *(unsigned long long*)&Ps[wave][c * 136 + nt * 16 + g * 4] = pk.u;
            pk.h[0] = __float22bfloat162_rn(make_float2(p1[0], p1[1]));
            pk.h[1] = __float22bfloat162_rn(make_float2(p1[2], p1[3]));
            pd[nt][0] = pk.w[0]; pd[nt][1] = pk.w[1];
        }
        l_part[0] += lp0;
        l_part[1] += lp1;

        // ---- PV strip 0 (P from LDS)
#pragma unroll
        for (int ks = 0; ks < 4; ++ks) {
            short8 pf = *(const short8*)&Ps[wave][c * 136 + ks * 32 + g * 8];
#pragma unroll
            for (int nt = 0; nt < 4; ++nt) {
                short8 vf = *(const short8*)&Vs[(nt * 16 + c) * 136 + ks * 32 + g * 8];
                o_acc[0][nt] = __builtin_amdgcn_mfma_f32_16x16x32_bf16(pf, vf, o_acc[0][nt], 0, 0, 0);
            }
        }
        // ---- strip-1 P regs -> LDS (per-wave private slot; lgkm-ordered)
#pragma unroll
        for (int nt = 0; nt < 8; ++nt) {
            union { unsigned long long u; unsigned w[2]; } pk;
            pk.w[0] = pd[nt][0]; pk.w[1] = pd[nt][1];
            *(unsigned long long*)&Ps[wave][c * 136 + nt * 16 + g * 4] = pk.u;
        }
        // ---- PV strip 1
#pragma unroll
        for (int ks = 0; ks < 4; ++ks) {
            short8 pf = *(const short8*)&Ps[wave][c * 136 + ks * 32 + g * 8];
#pragma unroll
            for (int nt = 0; nt < 4; ++nt) {
                short8 vf = *(const short8*)&Vs[(nt * 16 + c) * 136 + ks * 32 + g * 8];
                o_acc[1][nt] = __builtin_amdgcn_mfma_f32_16x16x32_bf16(pf, vf, o_acc[1][nt], 0, 0, 0);
            }
        }
    }

    // epilogue: reduce l across g-groups, broadcast, O/l -> a[b][s][h*64+d]
#pragma unroll
    for (int ss = 0; ss < 2; ++ss) {
        float l = l_part[ss];
        l += __shfl_xor(l, 16);
        l += __shfl_xor(l, 32);
        float linv = 1.0f / l;         // lane {c,c+16,c+32,c+48} hold l for q=rl0+c
        float inv[4];
#pragma unroll
        for (int r = 0; r < 4; ++r)
            inv[r] = __shfl(linv, g * 4 + r);   // q-in-strip = g*4+r lives at lane g*4+r
#pragma unroll
        for (int nt = 0; nt < 4; ++nt)
#pragma unroll
            for (int r = 0; r < 4; ++r) {
                int q = q0 + (wave * 2 + ss) * 16 + g * 4 + r;
                aout[(size_t)(b * 2048 + q) * 1024 + h * 64 + nt * 16 + c] =
                    f2bf(o_acc[ss][nt][r] * inv[r]);
            }
    }
}

// ---------------- proj GEMM: [8192,1024]@[1024,1024]^T + bias -> fp32 ----------------
__global__ __launch_bounds__(256) void gemm_proj_kernel(const ushort_t* __restrict__ A,
                                                        const ushort_t* __restrict__ Bt,
                                                        const float* __restrict__ bias,
                                                        float* __restrict__ Cout) {
    const int K = 1024, N = 1024, nbn = 8;
    __shared__ __align__(16) ushort_t As[128 * 32];
    __shared__ __align__(16) ushort_t Bs[128 * 32];
    int bm = blockIdx.x / nbn, bn = blockIdx.x % nbn;
    int m0 = bm << 7, n0 = bn << 7;
    int tid = threadIdx.x;
    int wave = tid >> 6, lane = tid & 63;
    int c = lane & 15, g = lane >> 4;
    int m_off = (wave & 1) << 6, n_off = (wave >> 1) << 6;
    int ldrow = lane >> 2;
    int ldk   = (lane & 3) << 3;

    floatx4 acc[4][4];
#pragma unroll
    for (int mi = 0; mi < 4; ++mi)
#pragma unroll
        for (int ni = 0; ni < 4; ++ni) {
            floatx4 z = {0.f, 0.f, 0.f, 0.f};
            acc[mi][ni] = z;
        }

    for (int kk = 0; kk < K; kk += 32) {
        __syncthreads();
#pragma unroll
        for (int j = 0; j < 2; ++j) {
            int chunk = wave * 2 + j;
            async_ld16(A  + (size_t)(m0 + chunk * 16 + ldrow) * K + kk + ldk, &As[chunk * 512]);
            async_ld16(Bt + (size_t)(n0 + chunk * 16 + ldrow) * K + kk + ldk, &Bs[chunk * 512]);
        }
        __syncthreads();
        short8 bf[4];
#pragma unroll
        for (int ni = 0; ni < 4; ++ni)
            bf[ni] = *(const short8*)&Bs[(n_off + ni * 16 + c) * 32 + g * 8];
#pragma unroll
        for (int mi = 0; mi < 4; ++mi) {
            short8 af = *(const short8*)&As[(m_off + mi * 16 + c) * 32 + g * 8];
#pragma unroll
            for (int ni = 0; ni < 4; ++ni)
                acc[mi][ni] = __builtin_amdgcn_mfma_f32_16x16x32_bf16(af, bf[ni], acc[mi][ni], 0, 0, 0);
        }
    }

    float bv[4];
#pragma unroll
    for (int ni = 0; ni < 4; ++ni) bv[ni] = bias[n0 + n_off + ni * 16 + c];
#pragma unroll
    for (int mi = 0; mi < 4; ++mi)
#pragma unroll
        for (int ni = 0; ni < 4; ++ni)
#pragma unroll
            for (int r = 0; r < 4; ++r) {
                int row = m0 + m_off + mi * 16 + g * 4 + r;
                int col = n0 + n_off + ni * 16 + c;
                Cout[(size_t)row * N + col] = acc[mi][ni][r] + bv[ni];
            }
}

extern "C" void kernel_launch(void* const* d_in, const int* in_sizes, int n_in,
                              void* d_out, int out_size, void* d_ws, size_t ws_size,
                              hipStream_t stream) {
    const float* x        = (const float*)d_in[0];
    const float* c_attn_w = (const float*)d_in[1];
    const float* c_attn_b = (const float*)d_in[2];
    const float* c_proj_w = (const float*)d_in[3];
    const float* c_proj_b = (const float*)d_in[4];
    float* out = (float*)d_out;

    char* ws = (char*)d_ws;
    ushort_t* xb     = (ushort_t*)(ws);              // 16 MB; reused as attn output 'a'
    ushort_t* wqkvT  = (ushort_t*)(ws + 16777216);   // 6 MB
    ushort_t* wprojT = (ushort_t*)(ws + 23068672);   // 2 MB
    ushort_t* qbuf   = (ushort_t*)(ws + 25165824);   // 16 MB  [bh][s][64]  (pre-scaled)
    ushort_t* kbuf   = (ushort_t*)(ws + 41943040);   // 16 MB  [bh][s][64]
    ushort_t* vtbuf  = (ushort_t*)(ws + 58720256);   // 16 MB  [bh][64][2048]

    prep_kernel<<<12288, 256, 0, stream>>>(x, c_attn_w, c_proj_w, xb, wqkvT, wprojT);
    gemm_qkv_kernel<<<64 * 24, 256, 0, stream>>>(xb, wqkvT, c_attn_b, qbuf, kbuf, vtbuf);
    attn_kernel<<<1024, 256, 0, stream>>>(qbuf, kbuf, vtbuf, xb);
    gemm_proj_kernel<<<64 * 8, 256, 0, stream>>>(xb, wprojT, c_proj_b, out);
}